// Round 6
// baseline (2539.299 us; speedup 1.0000x reference)
//
#include <hip/hip_runtime.h>
#include <hip/hip_bf16.h>
#include <cstdint>
#include <cstddef>

#define NN 50000     // nodes
#define EE 1000000   // edges
#define NB 2         // batch

#define MSTR 72      // activation tile stride (shorts): 144 B rows

// packed-weight layout (shorts): B-fragment order [kstep][ntile][lane][8]
#define P_E1 0
#define P_E2 10240
#define P_C1 14336
#define P_F1 18432
#define P_F2 26624
#define PK_TOTAL 30720

// d_ws byte offsets
#define WS_CNT   0
#define WS_OFF   200704
#define WS_CUR   401408
#define WS_EIDS  602112
#define WS_PK    4602112
#define WS_HB    4663552
// total ~17.5 MB

typedef __attribute__((ext_vector_type(8))) short short8;
typedef __attribute__((ext_vector_type(4))) float f32x4;

__device__ __forceinline__ float fast_rcp(float v) { return __builtin_amdgcn_rcpf(v); }
__device__ __forceinline__ float silu_f(float v) { return v * fast_rcp(1.0f + __expf(-v)); }
__device__ __forceinline__ float ssgn_f(float v) { return v * fast_rcp(1.0f + fabsf(v)); }

__device__ __forceinline__ short f2bf(float f) {
    __hip_bfloat16 h = __float2bfloat16(f);
    return *reinterpret_cast<short*>(&h);
}
__device__ __forceinline__ float bf2f(short s) {
    union { unsigned u; float f; } c; c.u = ((unsigned)(unsigned short)s) << 16; return c.f;
}
__device__ __forceinline__ short8 pack8(float4 a, float4 b) {
    short8 r;
    r[0] = f2bf(a.x); r[1] = f2bf(a.y); r[2] = f2bf(a.z); r[3] = f2bf(a.w);
    r[4] = f2bf(b.x); r[5] = f2bf(b.y); r[6] = f2bf(b.z); r[7] = f2bf(b.w);
    return r;
}

// G17: keep values live without cost (ablation anti-DCE sinks)
__device__ __forceinline__ void sink8(short8 v) {
    int4 i; __builtin_memcpy(&i, &v, 16);
    asm volatile("" :: "v"(i.x), "v"(i.y), "v"(i.z), "v"(i.w));
}
__device__ __forceinline__ void sinkf4(f32x4 v) {
    asm volatile("" :: "v"(v[0]), "v"(v[1]), "v"(v[2]), "v"(v[3]));
}

// ---------------------------------------------------------------------------
__global__ void conv_h(const float* __restrict__ h, short* __restrict__ hb16) {
    size_t i = ((size_t)blockIdx.x * 256 + threadIdx.x) * 8;
    float4 lo = *reinterpret_cast<const float4*>(h + i);
    float4 hi = *reinterpret_cast<const float4*>(h + i + 4);
    *reinterpret_cast<short8*>(hb16 + i) = pack8(lo, hi);
}

__global__ void hist_kernel(const int* __restrict__ ei, int* __restrict__ cnt_i) {
    int e = blockIdx.x * 256 + threadIdx.x;
    if (e < EE) atomicAdd(&cnt_i[ei[e]], 1);
}

__global__ void scan_kernel(const int* __restrict__ cnt_i,
                            int* __restrict__ off, int* __restrict__ cur) {
    __shared__ int part[1024];
    const int t = threadIdx.x;
    const int CH = (NN + 1023) / 1024;
    int base = t * CH;
    int s = 0;
    for (int j = 0; j < CH; j++) { int idx = base + j; if (idx < NN) s += cnt_i[idx]; }
    part[t] = s;
    __syncthreads();
    for (int d = 1; d < 1024; d <<= 1) {
        int v = (t >= d) ? part[t - d] : 0;
        __syncthreads();
        part[t] += v;
        __syncthreads();
    }
    int excl = (t == 0) ? 0 : part[t - 1];
    for (int j = 0; j < CH; j++) {
        int idx = base + j;
        if (idx < NN) { off[idx] = excl; cur[idx] = excl; excl += cnt_i[idx]; }
    }
    if (t == 1023) off[NN] = part[1023];
}

__global__ void scatter_kernel(const int* __restrict__ ei,
                               int* __restrict__ cur, int* __restrict__ eids) {
    int e = blockIdx.x * 256 + threadIdx.x;
    if (e < EE) {
        int p = atomicAdd(&cur[ei[e]], 1);
        eids[p] = e;
    }
}

__global__ void pack_weights(const float* __restrict__ w_e1,
                             const float* __restrict__ w_e2,
                             const float* __restrict__ w_c1,
                             const float* __restrict__ w_f1,
                             const float* __restrict__ w_f2,
                             short* __restrict__ pk)
{
    int g = blockIdx.x * 256 + threadIdx.x;
    const int G_E1 = 5 * 4 * 64, G_E2 = 2 * 4 * 64, G_C1 = 2 * 4 * 64;
    const int G_F1 = 4 * 4 * 64, G_F2 = 2 * 4 * 64;
    if (g >= G_E1 + G_E2 + G_C1 + G_F1 + G_F2) return;
    const float* W; int loc; int mat;
    if (g < G_E1)                        { W = w_e1; loc = g;                         mat = 0; }
    else if (g < G_E1+G_E2)              { W = w_e2; loc = g - G_E1;                  mat = 1; }
    else if (g < G_E1+G_E2+G_C1)         { W = w_c1; loc = g - G_E1 - G_E2;           mat = 2; }
    else if (g < G_E1+G_E2+G_C1+G_F1)    { W = w_f1; loc = g - G_E1 - G_E2 - G_C1;    mat = 3; }
    else                                 { W = w_f2; loc = g - G_E1-G_E2-G_C1-G_F1;   mat = 4; }
    int l = loc & 63, n = (loc >> 6) & 3, s = loc >> 8;
    short8 out;
    #pragma unroll
    for (int j = 0; j < 8; j++) {
        int kp = s * 32 + ((l >> 4) * 8) + j;
        int ko; bool valid;
        if (mat == 0) {
            if (kp < 128)      { ko = kp;     valid = true; }
            else if (kp < 144) { ko = kp + 1; valid = true; }
            else if (kp == 144){ ko = 128;    valid = true; }
            else               { ko = 0;      valid = false; }
        } else if (mat == 3) { ko = kp; valid = kp < 128; }
        else                 { ko = kp; valid = kp < 64; }
        float v = valid ? W[ko * 64 + (n * 16 + (l & 15))] : 0.0f;
        out[j] = f2bf(v);
    }
    *reinterpret_cast<short8*>(pk + (size_t)g * 8) = out;
}

// ---------------------------------------------------------------------------
// Edge kernel, phase-ablated variants:
//  V=0: full (real outputs), 1 pass.
//  V=3: all global loads only; V=2: +GEMM1+silu+t1-write; V=1: all but scatter.
//  V>0: read-only, asm-sinked, 2 independent edge chunks per wave (visibility).
// ---------------------------------------------------------------------------
template<int V>
__global__ __launch_bounds__(256, 4) void edge_kernel(
    const short* __restrict__ hb16, const float* __restrict__ x,
    const int* __restrict__ ei, const float* __restrict__ ea,
    const int* __restrict__ eids,
    const float* __restrict__ b_e1, const float* __restrict__ b_e2,
    const float* __restrict__ b_c1, const float* __restrict__ w_c2,
    const short* __restrict__ pk,
    const float* __restrict__ sm_p, const float* __restrict__ om_p,
    float* __restrict__ agg, float* __restrict__ xagg)
{
    __shared__ short smem[4][64 * MSTR];
    __shared__ float aux_a[4][256];
    const int wid  = threadIdx.x >> 6;
    const int lane = threadIdx.x & 63;
    short* sm  = smem[wid];
    float* aux = aux_a[wid];

    const int nwg = gridDim.x;
    const int q = nwg >> 3, r_ = nwg & 7;
    const int xcd = blockIdx.x & 7, kk = blockIdx.x >> 3;
    const int bswz = (xcd < r_ ? xcd * (q + 1) : r_ * (q + 1) + (xcd - r_) * q) + kk;

    const int WPB = EE / 64;
    const int TOTW = NB * WPB;             // 31250
    const int gw = bswz * 4 + wid;
    if (gw >= TOTW) return;

    const int l15 = lane & 15;
    const int gq  = lane >> 4;
    const int kg  = gq * 8;

    const int REPS = (V == 0) ? 1 : 2;
    #pragma unroll 1
    for (int rep = 0; rep < REPS; rep++) {
        int gww = gw + rep * (TOTW / 2);
        if (gww >= TOTW) gww -= TOTW;
        const int b  = gww / WPB;
        const int i0 = (gww - b * WPB) * 64;

        const int eid = eids[i0 + lane];
        const int row = ei[eid];
        const int col = ei[EE + eid];

        const float4 xr = *reinterpret_cast<const float4*>(x + ((size_t)b * NN + row) * 4);
        const float4 xc = *reinterpret_cast<const float4*>(x + ((size_t)b * NN + col) * 4);
        const float d0 = xr.x - xc.x, d1 = xr.y - xc.y, d2 = xr.z - xc.z, d3 = xr.w - xc.w;
        const float radial = d1 * d1 + d2 * d2 + d3 * d3 - d0 * d0;

        int rowi[4], coli[4], eidm[4];
        float radm[4];
        #pragma unroll
        for (int m = 0; m < 4; m++) {
            int src = m * 16 + l15;
            rowi[m] = __shfl(row, src);
            coli[m] = __shfl(col, src);
            eidm[m] = __shfl(eid, src);
            radm[m] = __shfl(radial, src);
        }
        const short* hbb = hb16 + (size_t)b * NN * 64;
        const short8* pke1 = reinterpret_cast<const short8*>(pk + P_E1);
        const short8* pke2 = reinterpret_cast<const short8*>(pk + P_E2);
        const short8* pkc1 = reinterpret_cast<const short8*>(pk + P_C1);

        // ---- GEMM1 ----
        f32x4 acc[4][4];
        #pragma unroll
        for (int n = 0; n < 4; n++) {
            float bias = b_e1[n * 16 + l15];
            #pragma unroll
            for (int m = 0; m < 4; m++) acc[m][n] = f32x4{bias, bias, bias, bias};
        }
        #pragma unroll
        for (int s = 0; s < 5; s++) {
            short8 afr[4];
            if (s < 4) {
                #pragma unroll
                for (int m = 0; m < 4; m++) {
                    int r = (s < 2) ? rowi[m] : coli[m];
                    afr[m] = *reinterpret_cast<const short8*>(
                        hbb + (size_t)r * 64 + (s & 1) * 32 + kg);
                }
            } else {
                #pragma unroll
                for (int m = 0; m < 4; m++) {
                    short8 v = short8{0, 0, 0, 0, 0, 0, 0, 0};
                    if (gq < 2) {
                        const float* src = ea + ((size_t)b * EE + eidm[m]) * 16 + gq * 8;
                        float4 lo = *reinterpret_cast<const float4*>(src);
                        float4 hi = *reinterpret_cast<const float4*>(src + 4);
                        v = pack8(lo, hi);
                    } else if (gq == 2) {
                        v[0] = f2bf(radm[m]);
                    }
                    afr[m] = v;
                }
            }
            if constexpr (V == 3) {
                #pragma unroll
                for (int m = 0; m < 4; m++) sink8(afr[m]);
                #pragma unroll
                for (int n = 0; n < 4; n++) sink8(pke1[(s * 4 + n) * 64 + lane]);
            } else {
                __builtin_amdgcn_s_setprio(1);
                #pragma unroll
                for (int n = 0; n < 4; n++) {
                    short8 bfr = pke1[(s * 4 + n) * 64 + lane];
                    #pragma unroll
                    for (int m = 0; m < 4; m++)
                        acc[m][n] = __builtin_amdgcn_mfma_f32_16x16x32_bf16(afr[m], bfr, acc[m][n], 0, 0, 0);
                }
                __builtin_amdgcn_s_setprio(0);
            }
        }
        if constexpr (V == 3) {
            // remaining weight-fragment loads (GEMM2/3) — issue + sink
            #pragma unroll
            for (int f = 0; f < 8; f++) { sink8(pke2[f * 64 + lane]); sink8(pkc1[f * 64 + lane]); }
            asm volatile("" :: "v"(radial));
            continue;
        }

        // ---- t1 = silu(acc) -> LDS ----
        #pragma unroll
        for (int m = 0; m < 4; m++)
            #pragma unroll
            for (int n = 0; n < 4; n++)
                #pragma unroll
                for (int r = 0; r < 4; r++)
                    sm[(m * 16 + gq * 4 + r) * MSTR + n * 16 + l15] = f2bf(silu_f(acc[m][n][r]));
        asm volatile("s_waitcnt lgkmcnt(0)" ::: "memory");

        if constexpr (V == 2) {
            #pragma unroll
            for (int m = 0; m < 4; m++)
                #pragma unroll
                for (int n = 0; n < 4; n++) sinkf4(acc[m][n]);
            asm volatile("" ::: "memory");
            continue;
        }

        // ---- GEMM2 ----
        f32x4 acc2[4][4];
        #pragma unroll
        for (int n = 0; n < 4; n++) {
            float bias = b_e2[n * 16 + l15];
            #pragma unroll
            for (int m = 0; m < 4; m++) acc2[m][n] = f32x4{bias, bias, bias, bias};
        }
        #pragma unroll
        for (int s = 0; s < 2; s++) {
            short8 afr[4];
            #pragma unroll
            for (int m = 0; m < 4; m++)
                afr[m] = *reinterpret_cast<const short8*>(sm + (m * 16 + l15) * MSTR + s * 32 + kg);
            __builtin_amdgcn_s_setprio(1);
            #pragma unroll
            for (int n = 0; n < 4; n++) {
                short8 bfr = pke2[(s * 4 + n) * 64 + lane];
                #pragma unroll
                for (int m = 0; m < 4; m++)
                    acc2[m][n] = __builtin_amdgcn_mfma_f32_16x16x32_bf16(afr[m], bfr, acc2[m][n], 0, 0, 0);
            }
            __builtin_amdgcn_s_setprio(0);
        }
        asm volatile("s_waitcnt lgkmcnt(0)" ::: "memory");

        // ---- m = softsign(acc2) -> LDS ----
        #pragma unroll
        for (int m = 0; m < 4; m++)
            #pragma unroll
            for (int n = 0; n < 4; n++)
                #pragma unroll
                for (int r = 0; r < 4; r++)
                    sm[(m * 16 + gq * 4 + r) * MSTR + n * 16 + l15] = f2bf(ssgn_f(acc2[m][n][r]));
        asm volatile("s_waitcnt lgkmcnt(0)" ::: "memory");

        // ---- GEMM3 + phi ----
        f32x4 acc3[4][4];
        #pragma unroll
        for (int n = 0; n < 4; n++) {
            float bias = b_c1[n * 16 + l15];
            #pragma unroll
            for (int m = 0; m < 4; m++) acc3[m][n] = f32x4{bias, bias, bias, bias};
        }
        #pragma unroll
        for (int s = 0; s < 2; s++) {
            short8 afr[4];
            #pragma unroll
            for (int m = 0; m < 4; m++)
                afr[m] = *reinterpret_cast<const short8*>(sm + (m * 16 + l15) * MSTR + s * 32 + kg);
            __builtin_amdgcn_s_setprio(1);
            #pragma unroll
            for (int n = 0; n < 4; n++) {
                short8 bfr = pkc1[(s * 4 + n) * 64 + lane];
                #pragma unroll
                for (int m = 0; m < 4; m++)
                    acc3[m][n] = __builtin_amdgcn_mfma_f32_16x16x32_bf16(afr[m], bfr, acc3[m][n], 0, 0, 0);
            }
            __builtin_amdgcn_s_setprio(0);
        }
        float wc2v[4];
        #pragma unroll
        for (int n = 0; n < 4; n++) wc2v[n] = w_c2[n * 16 + l15];
        #pragma unroll
        for (int m = 0; m < 4; m++)
            #pragma unroll
            for (int r = 0; r < 4; r++) {
                float v = 0.0f;
                #pragma unroll
                for (int n = 0; n < 4; n++) v = fmaf(silu_f(acc3[m][n][r]), wc2v[n], v);
                v += __shfl_xor(v, 1); v += __shfl_xor(v, 2);
                v += __shfl_xor(v, 4); v += __shfl_xor(v, 8);
                if (l15 == 0) aux[m * 16 + gq * 4 + r] = v;
            }
        asm volatile("s_waitcnt lgkmcnt(0)" ::: "memory");
        const float phiv = aux[lane];
        asm volatile("s_waitcnt lgkmcnt(0)" ::: "memory");

        const float smv = sm_p[0], omv = om_p[0];
        aux[lane * 4 + 0] = (smv * xr.x + omv * xc.x) * phiv;
        aux[lane * 4 + 1] = (smv * xr.y + omv * xc.y) * phiv;
        aux[lane * 4 + 2] = (smv * xr.z + omv * xc.z) * phiv;
        aux[lane * 4 + 3] = (smv * xr.w + omv * xc.w) * phiv;
        asm volatile("s_waitcnt lgkmcnt(0)" ::: "memory");

        if constexpr (V == 1) {
            asm volatile("" :: "v"(phiv));
            asm volatile("" ::: "memory");
            continue;
        }

        // ---- ballot run-merged scatter (V==0 only) ----
        int nrow = __shfl_down(row, 1);
        unsigned long long bmask = __ballot((lane == 63) || (row != nrow));
        float* aggb = agg + (size_t)b * NN * 64;
        float* xb   = xagg + (size_t)b * NN * 4;
        float mv = 0.0f, xv = 0.0f;
        #pragma unroll
        for (int e = 0; e < 64; e++) {
            mv += bf2f(sm[e * MSTR + lane]);
            float t = aux[e * 4 + (lane & 3)];
            xv += (lane < 4) ? t : 0.0f;
            if ((bmask >> e) & 1ull) {
                int re = __shfl(row, e);
                atomicAdd(aggb + (size_t)re * 64 + lane, mv);
                if (lane < 4) atomicAdd(xb + (size_t)re * 4 + lane, xv);
                mv = 0.0f; xv = 0.0f;
            }
        }
    }
}

// ---------------------------------------------------------------------------
__global__ __launch_bounds__(256, 4) void node_kernel(
    const short* __restrict__ hb16, const float* __restrict__ x,
    const float* __restrict__ b_f1, const float* __restrict__ b_f2,
    const short* __restrict__ pk,
    const int* __restrict__ off,
    float* out_h, float* out_x)
{
    __shared__ short smem[4][64 * MSTR];
    const int wid  = threadIdx.x >> 6;
    const int lane = threadIdx.x & 63;
    short* sm = smem[wid];

    const int WN = (NN + 63) / 64;
    const int gw = blockIdx.x * 4 + wid;
    if (gw >= NB * WN) return;
    const int b  = gw / WN;
    const int n0 = (gw - b * WN) * 64;

    const int l15 = lane & 15;
    const int gq  = lane >> 4;
    const int kg  = gq * 8;

    const short* hbb  = hb16 + (size_t)b * NN * 64;
    const float* aggb = out_h + (size_t)b * NN * 64;

    f32x4 acc[4][4];
    #pragma unroll
    for (int n = 0; n < 4; n++) {
        float bias = b_f1[n * 16 + l15];
        #pragma unroll
        for (int m = 0; m < 4; m++) acc[m][n] = f32x4{bias, bias, bias, bias};
    }
    const short8* pkf1 = reinterpret_cast<const short8*>(pk + P_F1);
    #pragma unroll
    for (int s = 0; s < 4; s++) {
        short8 afr[4];
        #pragma unroll
        for (int m = 0; m < 4; m++) {
            int nd = n0 + m * 16 + l15;
            if (nd >= NN) nd = NN - 1;
            if (s < 2) {
                afr[m] = *reinterpret_cast<const short8*>(
                    hbb + (size_t)nd * 64 + s * 32 + kg);
            } else {
                const float* base = aggb + (size_t)nd * 64 + (s & 1) * 32 + kg;
                float4 lo = *reinterpret_cast<const float4*>(base);
                float4 hi = *reinterpret_cast<const float4*>(base + 4);
                afr[m] = pack8(lo, hi);
            }
        }
        __builtin_amdgcn_s_setprio(1);
        #pragma unroll
        for (int n = 0; n < 4; n++) {
            short8 bfr = pkf1[(s * 4 + n) * 64 + lane];
            #pragma unroll
            for (int m = 0; m < 4; m++)
                acc[m][n] = __builtin_amdgcn_mfma_f32_16x16x32_bf16(afr[m], bfr, acc[m][n], 0, 0, 0);
        }
        __builtin_amdgcn_s_setprio(0);
    }

    #pragma unroll
    for (int m = 0; m < 4; m++)
        #pragma unroll
        for (int n = 0; n < 4; n++)
            #pragma unroll
            for (int r = 0; r < 4; r++)
                sm[(m * 16 + gq * 4 + r) * MSTR + n * 16 + l15] = f2bf(silu_f(acc[m][n][r]));
    asm volatile("s_waitcnt lgkmcnt(0)" ::: "memory");

    f32x4 acc2[4][4];
    #pragma unroll
    for (int n = 0; n < 4; n++) {
        float bias = b_f2[n * 16 + l15];
        #pragma unroll
        for (int m = 0; m < 4; m++) acc2[m][n] = f32x4{bias, bias, bias, bias};
    }
    const short8* pkf2 = reinterpret_cast<const short8*>(pk + P_F2);
    #pragma unroll
    for (int s = 0; s < 2; s++) {
        short8 afr[4];
        #pragma unroll
        for (int m = 0; m < 4; m++)
            afr[m] = *reinterpret_cast<const short8*>(sm + (m * 16 + l15) * MSTR + s * 32 + kg);
        __builtin_amdgcn_s_setprio(1);
        #pragma unroll
        for (int n = 0; n < 4; n++) {
            short8 bfr = pkf2[(s * 4 + n) * 64 + lane];
            #pragma unroll
            for (int m = 0; m < 4; m++)
                acc2[m][n] = __builtin_amdgcn_mfma_f32_16x16x32_bf16(afr[m], bfr, acc2[m][n], 0, 0, 0);
        }
        __builtin_amdgcn_s_setprio(0);
    }

    float* ohb = out_h + (size_t)b * NN * 64;
    #pragma unroll
    for (int m = 0; m < 4; m++)
        #pragma unroll
        for (int r = 0; r < 4; r++) {
            int nd = n0 + m * 16 + gq * 4 + r;
            if (nd < NN) {
                #pragma unroll
                for (int n = 0; n < 4; n++)
                    ohb[(size_t)nd * 64 + n * 16 + l15] = ssgn_f(acc2[m][n][r]);
            }
        }

    const int node = n0 + lane;
    if (node < NN) {
        int c_i = off[node + 1] - off[node];
        float c = (float)(c_i < 1 ? 1 : c_i);
        float invc = fast_rcp(c);
        const float4 xv = *reinterpret_cast<const float4*>(x + ((size_t)b * NN + node) * 4);
        float* xop = out_x + ((size_t)b * NN + node) * 4;
        float4 xa = *reinterpret_cast<float4*>(xop);
        float4 r;
        r.x = xv.x + xa.x * invc;
        r.y = xv.y + xa.y * invc;
        r.z = xv.z + xa.z * invc;
        r.w = xv.w + xa.w * invc;
        *reinterpret_cast<float4*>(xop) = r;
    }
}

// ---------------------------------------------------------------------------
extern "C" void kernel_launch(void* const* d_in, const int* in_sizes, int n_in,
                              void* d_out, int out_size, void* d_ws, size_t ws_size,
                              hipStream_t stream) {
    const float* h    = (const float*)d_in[0];
    const float* x    = (const float*)d_in[1];
    const int*   ei   = (const int*)d_in[2];
    const float* ea   = (const float*)d_in[3];
    const float* w_e1 = (const float*)d_in[4];
    const float* b_e1 = (const float*)d_in[5];
    const float* w_e2 = (const float*)d_in[6];
    const float* b_e2 = (const float*)d_in[7];
    const float* w_f1 = (const float*)d_in[8];
    const float* b_f1 = (const float*)d_in[9];
    const float* w_f2 = (const float*)d_in[10];
    const float* b_f2 = (const float*)d_in[11];
    const float* w_c1 = (const float*)d_in[12];
    const float* b_c1 = (const float*)d_in[13];
    const float* w_c2 = (const float*)d_in[14];
    const float* smp  = (const float*)d_in[15];
    const float* omp  = (const float*)d_in[16];

    float* out   = (float*)d_out;
    float* agg   = out;
    float* out_x = out + (size_t)NB * NN * 64;

    char* ws = (char*)d_ws;
    int*   cnt_i = (int*)(ws + WS_CNT);
    int*   off   = (int*)(ws + WS_OFF);
    int*   cur   = (int*)(ws + WS_CUR);
    int*   eids  = (int*)(ws + WS_EIDS);
    short* pk    = (short*)(ws + WS_PK);
    short* hb16  = (short*)(ws + WS_HB);

    hipMemsetAsync(d_out, 0, (size_t)out_size * sizeof(float), stream);
    hipMemsetAsync(cnt_i, 0, (size_t)NN * sizeof(int), stream);

    pack_weights<<<15, 256, 0, stream>>>(w_e1, w_e2, w_c1, w_f1, w_f2, pk);
    conv_h<<<3125, 256, 0, stream>>>(h, hb16);

    const int eb = (EE + 255) / 256;
    hist_kernel<<<eb, 256, 0, stream>>>(ei, cnt_i);
    scan_kernel<<<1, 1024, 0, stream>>>(cnt_i, off, cur);
    scatter_kernel<<<eb, 256, 0, stream>>>(ei, cur, eids);

    const int edge_waves = NB * (EE / 64);            // 31250
    const int edge_blocks = (edge_waves + 3) / 4;     // 7813

    // --- diagnostic ablation dispatches (read-only, no output writes) ---
    edge_kernel<3><<<edge_blocks, 256, 0, stream>>>(
        hb16, x, ei, ea, eids, b_e1, b_e2, b_c1, w_c2, pk, smp, omp, agg, out_x);
    edge_kernel<2><<<edge_blocks, 256, 0, stream>>>(
        hb16, x, ei, ea, eids, b_e1, b_e2, b_c1, w_c2, pk, smp, omp, agg, out_x);
    edge_kernel<1><<<edge_blocks, 256, 0, stream>>>(
        hb16, x, ei, ea, eids, b_e1, b_e2, b_c1, w_c2, pk, smp, omp, agg, out_x);

    // --- real edge pass ---
    edge_kernel<0><<<edge_blocks, 256, 0, stream>>>(
        hb16, x, ei, ea, eids, b_e1, b_e2, b_c1, w_c2, pk, smp, omp, agg, out_x);

    const int node_waves = NB * ((NN + 63) / 64);
    const int node_blocks = (node_waves + 3) / 4;
    node_kernel<<<node_blocks, 256, 0, stream>>>(
        hb16, x, b_f1, b_f2, pk, off, agg, out_x);
}

// Round 7
// 584.626 us; speedup vs baseline: 4.3435x; 4.3435x over previous
//
#include <hip/hip_runtime.h>
#include <hip/hip_bf16.h>
#include <cstdint>
#include <cstddef>

#define NN 50000     // nodes
#define EE 1000000   // edges
#define NB 2         // batch

#define MSTR 72      // activation tile stride (shorts): 144 B rows

// packed-weight layout (shorts): B-fragment order [kstep][ntile][lane][8]
#define P_E1 0
#define P_E2 10240
#define P_C1 14336
#define P_F1 18432
#define P_F2 26624
#define PK_TOTAL 30720

// d_ws byte offsets
#define WS_CNT   0
#define WS_OFF   200704
#define WS_CUR   401408
#define WS_EIDS  602112
#define WS_PK    4602112
#define WS_HB    4663552
// total ~17.5 MB

typedef __attribute__((ext_vector_type(8))) short short8;
typedef __attribute__((ext_vector_type(4))) float f32x4;

__device__ __forceinline__ float fast_rcp(float v) { return __builtin_amdgcn_rcpf(v); }
__device__ __forceinline__ float silu_f(float v) { return v * fast_rcp(1.0f + __expf(-v)); }
__device__ __forceinline__ float ssgn_f(float v) { return v * fast_rcp(1.0f + fabsf(v)); }

__device__ __forceinline__ short f2bf(float f) {
    __hip_bfloat16 h = __float2bfloat16(f);
    return *reinterpret_cast<short*>(&h);
}
__device__ __forceinline__ float bf2f(short s) {
    union { unsigned u; float f; } c; c.u = ((unsigned)(unsigned short)s) << 16; return c.f;
}
__device__ __forceinline__ short8 pack8(float4 a, float4 b) {
    short8 r;
    r[0] = f2bf(a.x); r[1] = f2bf(a.y); r[2] = f2bf(a.z); r[3] = f2bf(a.w);
    r[4] = f2bf(b.x); r[5] = f2bf(b.y); r[6] = f2bf(b.z); r[7] = f2bf(b.w);
    return r;
}

// ---------------------------------------------------------------------------
__global__ void conv_h(const float* __restrict__ h, short* __restrict__ hb16) {
    size_t i = ((size_t)blockIdx.x * 256 + threadIdx.x) * 8;
    float4 lo = *reinterpret_cast<const float4*>(h + i);
    float4 hi = *reinterpret_cast<const float4*>(h + i + 4);
    *reinterpret_cast<short8*>(hb16 + i) = pack8(lo, hi);
}

__global__ void hist_kernel(const int* __restrict__ ei, int* __restrict__ cnt_i) {
    int e = blockIdx.x * 256 + threadIdx.x;
    if (e < EE) atomicAdd(&cnt_i[ei[e]], 1);
}

__global__ void scan_kernel(const int* __restrict__ cnt_i,
                            int* __restrict__ off, int* __restrict__ cur) {
    __shared__ int part[1024];
    const int t = threadIdx.x;
    const int CH = (NN + 1023) / 1024;
    int base = t * CH;
    int s = 0;
    for (int j = 0; j < CH; j++) { int idx = base + j; if (idx < NN) s += cnt_i[idx]; }
    part[t] = s;
    __syncthreads();
    for (int d = 1; d < 1024; d <<= 1) {
        int v = (t >= d) ? part[t - d] : 0;
        __syncthreads();
        part[t] += v;
        __syncthreads();
    }
    int excl = (t == 0) ? 0 : part[t - 1];
    for (int j = 0; j < CH; j++) {
        int idx = base + j;
        if (idx < NN) { off[idx] = excl; cur[idx] = excl; excl += cnt_i[idx]; }
    }
    if (t == 1023) off[NN] = part[1023];
}

__global__ void scatter_kernel(const int* __restrict__ ei,
                               int* __restrict__ cur, int* __restrict__ eids) {
    int e = blockIdx.x * 256 + threadIdx.x;
    if (e < EE) {
        int p = atomicAdd(&cur[ei[e]], 1);
        eids[p] = e;
    }
}

__global__ void pack_weights(const float* __restrict__ w_e1,
                             const float* __restrict__ w_e2,
                             const float* __restrict__ w_c1,
                             const float* __restrict__ w_f1,
                             const float* __restrict__ w_f2,
                             short* __restrict__ pk)
{
    int g = blockIdx.x * 256 + threadIdx.x;
    const int G_E1 = 5 * 4 * 64, G_E2 = 2 * 4 * 64, G_C1 = 2 * 4 * 64;
    const int G_F1 = 4 * 4 * 64, G_F2 = 2 * 4 * 64;
    if (g >= G_E1 + G_E2 + G_C1 + G_F1 + G_F2) return;
    const float* W; int loc; int mat;
    if (g < G_E1)                        { W = w_e1; loc = g;                         mat = 0; }
    else if (g < G_E1+G_E2)              { W = w_e2; loc = g - G_E1;                  mat = 1; }
    else if (g < G_E1+G_E2+G_C1)         { W = w_c1; loc = g - G_E1 - G_E2;           mat = 2; }
    else if (g < G_E1+G_E2+G_C1+G_F1)    { W = w_f1; loc = g - G_E1 - G_E2 - G_C1;    mat = 3; }
    else                                 { W = w_f2; loc = g - G_E1-G_E2-G_C1-G_F1;   mat = 4; }
    int l = loc & 63, n = (loc >> 6) & 3, s = loc >> 8;
    short8 out;
    #pragma unroll
    for (int j = 0; j < 8; j++) {
        int kp = s * 32 + ((l >> 4) * 8) + j;
        int ko; bool valid;
        if (mat == 0) {
            if (kp < 128)      { ko = kp;     valid = true; }
            else if (kp < 144) { ko = kp + 1; valid = true; }
            else if (kp == 144){ ko = 128;    valid = true; }
            else               { ko = 0;      valid = false; }
        } else if (mat == 3) { ko = kp; valid = kp < 128; }
        else                 { ko = kp; valid = kp < 64; }
        float v = valid ? W[ko * 64 + (n * 16 + (l & 15))] : 0.0f;
        out[j] = f2bf(v);
    }
    *reinterpret_cast<short8*>(pk + (size_t)g * 8) = out;
}

// ---------------------------------------------------------------------------
// Edge kernel: all GEMM1 A-fragments loaded up-front into registers
// (one latency exposure), then MFMA sweep. launch_bounds(256,3) frees VGPRs.
// ---------------------------------------------------------------------------
__global__ __launch_bounds__(256, 3) void edge_kernel(
    const short* __restrict__ hb16, const float* __restrict__ x,
    const int* __restrict__ ei, const float* __restrict__ ea,
    const int* __restrict__ eids,
    const float* __restrict__ b_e1, const float* __restrict__ b_e2,
    const float* __restrict__ b_c1, const float* __restrict__ w_c2,
    const short* __restrict__ pk,
    const float* __restrict__ sm_p, const float* __restrict__ om_p,
    float* __restrict__ agg, float* __restrict__ xagg)
{
    __shared__ short smem[4][64 * MSTR];
    __shared__ float aux_a[4][256];
    const int wid  = threadIdx.x >> 6;
    const int lane = threadIdx.x & 63;
    short* sm  = smem[wid];
    float* aux = aux_a[wid];

    const int nwg = gridDim.x;
    const int q = nwg >> 3, r_ = nwg & 7;
    const int xcd = blockIdx.x & 7, kk = blockIdx.x >> 3;
    const int bswz = (xcd < r_ ? xcd * (q + 1) : r_ * (q + 1) + (xcd - r_) * q) + kk;

    const int WPB = EE / 64;
    const int gw = bswz * 4 + wid;
    if (gw >= NB * WPB) return;            // no barriers anywhere: safe
    const int b  = gw / WPB;
    const int i0 = (gw - b * WPB) * 64;

    const int l15 = lane & 15;
    const int gq  = lane >> 4;
    const int kg  = gq * 8;

    const int eid = eids[i0 + lane];
    const int row = ei[eid];
    const int col = ei[EE + eid];

    const float4 xr = *reinterpret_cast<const float4*>(x + ((size_t)b * NN + row) * 4);
    const float4 xc = *reinterpret_cast<const float4*>(x + ((size_t)b * NN + col) * 4);
    const float d0 = xr.x - xc.x, d1 = xr.y - xc.y, d2 = xr.z - xc.z, d3 = xr.w - xc.w;
    const float radial = d1 * d1 + d2 * d2 + d3 * d3 - d0 * d0;

    int rowi[4], coli[4], eidm[4];
    float radm[4];
    #pragma unroll
    for (int m = 0; m < 4; m++) {
        int src = m * 16 + l15;
        rowi[m] = __shfl(row, src);
        coli[m] = __shfl(col, src);
        eidm[m] = __shfl(eid, src);
        radm[m] = __shfl(radial, src);
    }
    const short* hbb = hb16 + (size_t)b * NN * 64;
    const short8* pke1 = reinterpret_cast<const short8*>(pk + P_E1);
    const short8* pke2 = reinterpret_cast<const short8*>(pk + P_E2);
    const short8* pkc1 = reinterpret_cast<const short8*>(pk + P_C1);

    // ---- GEMM1: load ALL A-fragments first (single latency exposure) ----
    short8 afr_all[5][4];
    // tail (ea: HBM-random, longest latency -> issue first)
    #pragma unroll
    for (int m = 0; m < 4; m++) {
        short8 v = short8{0, 0, 0, 0, 0, 0, 0, 0};
        if (gq < 2) {
            const float* src = ea + ((size_t)b * EE + eidm[m]) * 16 + gq * 8;
            float4 lo = *reinterpret_cast<const float4*>(src);
            float4 hi = *reinterpret_cast<const float4*>(src + 4);
            v = pack8(lo, hi);
        } else if (gq == 2) {
            v[0] = f2bf(radm[m]);
        }
        afr_all[4][m] = v;
    }
    #pragma unroll
    for (int s = 0; s < 4; s++) {
        #pragma unroll
        for (int m = 0; m < 4; m++) {
            int r = (s < 2) ? rowi[m] : coli[m];
            afr_all[s][m] = *reinterpret_cast<const short8*>(
                hbb + (size_t)r * 64 + (s & 1) * 32 + kg);
        }
    }

    f32x4 acc[4][4];
    #pragma unroll
    for (int n = 0; n < 4; n++) {
        float bias = b_e1[n * 16 + l15];
        #pragma unroll
        for (int m = 0; m < 4; m++) acc[m][n] = f32x4{bias, bias, bias, bias};
    }
    #pragma unroll
    for (int s = 0; s < 5; s++) {
        __builtin_amdgcn_s_setprio(1);
        #pragma unroll
        for (int n = 0; n < 4; n++) {
            short8 bfr = pke1[(s * 4 + n) * 64 + lane];
            #pragma unroll
            for (int m = 0; m < 4; m++)
                acc[m][n] = __builtin_amdgcn_mfma_f32_16x16x32_bf16(afr_all[s][m], bfr, acc[m][n], 0, 0, 0);
        }
        __builtin_amdgcn_s_setprio(0);
    }

    // ---- t1 = silu(acc) -> LDS ----
    #pragma unroll
    for (int m = 0; m < 4; m++)
        #pragma unroll
        for (int n = 0; n < 4; n++)
            #pragma unroll
            for (int r = 0; r < 4; r++)
                sm[(m * 16 + gq * 4 + r) * MSTR + n * 16 + l15] = f2bf(silu_f(acc[m][n][r]));
    asm volatile("s_waitcnt lgkmcnt(0)" ::: "memory");

    // ---- GEMM2 ----
    f32x4 acc2[4][4];
    #pragma unroll
    for (int n = 0; n < 4; n++) {
        float bias = b_e2[n * 16 + l15];
        #pragma unroll
        for (int m = 0; m < 4; m++) acc2[m][n] = f32x4{bias, bias, bias, bias};
    }
    #pragma unroll
    for (int s = 0; s < 2; s++) {
        short8 afr[4];
        #pragma unroll
        for (int m = 0; m < 4; m++)
            afr[m] = *reinterpret_cast<const short8*>(sm + (m * 16 + l15) * MSTR + s * 32 + kg);
        __builtin_amdgcn_s_setprio(1);
        #pragma unroll
        for (int n = 0; n < 4; n++) {
            short8 bfr = pke2[(s * 4 + n) * 64 + lane];
            #pragma unroll
            for (int m = 0; m < 4; m++)
                acc2[m][n] = __builtin_amdgcn_mfma_f32_16x16x32_bf16(afr[m], bfr, acc2[m][n], 0, 0, 0);
        }
        __builtin_amdgcn_s_setprio(0);
    }
    asm volatile("s_waitcnt lgkmcnt(0)" ::: "memory");

    // ---- m = softsign(acc2) -> LDS ----
    #pragma unroll
    for (int m = 0; m < 4; m++)
        #pragma unroll
        for (int n = 0; n < 4; n++)
            #pragma unroll
            for (int r = 0; r < 4; r++)
                sm[(m * 16 + gq * 4 + r) * MSTR + n * 16 + l15] = f2bf(ssgn_f(acc2[m][n][r]));
    asm volatile("s_waitcnt lgkmcnt(0)" ::: "memory");

    // ---- GEMM3 + phi ----
    f32x4 acc3[4][4];
    #pragma unroll
    for (int n = 0; n < 4; n++) {
        float bias = b_c1[n * 16 + l15];
        #pragma unroll
        for (int m = 0; m < 4; m++) acc3[m][n] = f32x4{bias, bias, bias, bias};
    }
    #pragma unroll
    for (int s = 0; s < 2; s++) {
        short8 afr[4];
        #pragma unroll
        for (int m = 0; m < 4; m++)
            afr[m] = *reinterpret_cast<const short8*>(sm + (m * 16 + l15) * MSTR + s * 32 + kg);
        __builtin_amdgcn_s_setprio(1);
        #pragma unroll
        for (int n = 0; n < 4; n++) {
            short8 bfr = pkc1[(s * 4 + n) * 64 + lane];
            #pragma unroll
            for (int m = 0; m < 4; m++)
                acc3[m][n] = __builtin_amdgcn_mfma_f32_16x16x32_bf16(afr[m], bfr, acc3[m][n], 0, 0, 0);
        }
        __builtin_amdgcn_s_setprio(0);
    }
    float wc2v[4];
    #pragma unroll
    for (int n = 0; n < 4; n++) wc2v[n] = w_c2[n * 16 + l15];
    #pragma unroll
    for (int m = 0; m < 4; m++)
        #pragma unroll
        for (int r = 0; r < 4; r++) {
            float v = 0.0f;
            #pragma unroll
            for (int n = 0; n < 4; n++) v = fmaf(silu_f(acc3[m][n][r]), wc2v[n], v);
            v += __shfl_xor(v, 1); v += __shfl_xor(v, 2);
            v += __shfl_xor(v, 4); v += __shfl_xor(v, 8);
            if (l15 == 0) aux[m * 16 + gq * 4 + r] = v;
        }
    asm volatile("s_waitcnt lgkmcnt(0)" ::: "memory");
    const float phiv = aux[lane];
    asm volatile("s_waitcnt lgkmcnt(0)" ::: "memory");

    const float smv = sm_p[0], omv = om_p[0];
    aux[lane * 4 + 0] = (smv * xr.x + omv * xc.x) * phiv;
    aux[lane * 4 + 1] = (smv * xr.y + omv * xc.y) * phiv;
    aux[lane * 4 + 2] = (smv * xr.z + omv * xc.z) * phiv;
    aux[lane * 4 + 3] = (smv * xr.w + omv * xc.w) * phiv;
    asm volatile("s_waitcnt lgkmcnt(0)" ::: "memory");

    // ---- ballot run-merged scatter ----
    int nrow = __shfl_down(row, 1);
    unsigned long long bmask = __ballot((lane == 63) || (row != nrow));
    float* aggb = agg + (size_t)b * NN * 64;
    float* xb   = xagg + (size_t)b * NN * 4;
    float mv = 0.0f, xv = 0.0f;
    #pragma unroll
    for (int e = 0; e < 64; e++) {
        mv += bf2f(sm[e * MSTR + lane]);
        float t = aux[e * 4 + (lane & 3)];
        xv += (lane < 4) ? t : 0.0f;
        if ((bmask >> e) & 1ull) {
            int re = __shfl(row, e);
            atomicAdd(aggb + (size_t)re * 64 + lane, mv);
            if (lane < 4) atomicAdd(xb + (size_t)re * 4 + lane, xv);
            mv = 0.0f; xv = 0.0f;
        }
    }
}

// ---------------------------------------------------------------------------
__global__ __launch_bounds__(256, 4) void node_kernel(
    const short* __restrict__ hb16, const float* __restrict__ x,
    const float* __restrict__ b_f1, const float* __restrict__ b_f2,
    const short* __restrict__ pk,
    const int* __restrict__ off,
    float* out_h, float* out_x)
{
    __shared__ short smem[4][64 * MSTR];
    const int wid  = threadIdx.x >> 6;
    const int lane = threadIdx.x & 63;
    short* sm = smem[wid];

    const int WN = (NN + 63) / 64;
    const int gw = blockIdx.x * 4 + wid;
    if (gw >= NB * WN) return;
    const int b  = gw / WN;
    const int n0 = (gw - b * WN) * 64;

    const int l15 = lane & 15;
    const int gq  = lane >> 4;
    const int kg  = gq * 8;

    const short* hbb  = hb16 + (size_t)b * NN * 64;
    const float* aggb = out_h + (size_t)b * NN * 64;

    f32x4 acc[4][4];
    #pragma unroll
    for (int n = 0; n < 4; n++) {
        float bias = b_f1[n * 16 + l15];
        #pragma unroll
        for (int m = 0; m < 4; m++) acc[m][n] = f32x4{bias, bias, bias, bias};
    }
    const short8* pkf1 = reinterpret_cast<const short8*>(pk + P_F1);
    #pragma unroll
    for (int s = 0; s < 4; s++) {
        short8 afr[4];
        #pragma unroll
        for (int m = 0; m < 4; m++) {
            int nd = n0 + m * 16 + l15;
            if (nd >= NN) nd = NN - 1;
            if (s < 2) {
                afr[m] = *reinterpret_cast<const short8*>(
                    hbb + (size_t)nd * 64 + s * 32 + kg);
            } else {
                const float* base = aggb + (size_t)nd * 64 + (s & 1) * 32 + kg;
                float4 lo = *reinterpret_cast<const float4*>(base);
                float4 hi = *reinterpret_cast<const float4*>(base + 4);
                afr[m] = pack8(lo, hi);
            }
        }
        __builtin_amdgcn_s_setprio(1);
        #pragma unroll
        for (int n = 0; n < 4; n++) {
            short8 bfr = pkf1[(s * 4 + n) * 64 + lane];
            #pragma unroll
            for (int m = 0; m < 4; m++)
                acc[m][n] = __builtin_amdgcn_mfma_f32_16x16x32_bf16(afr[m], bfr, acc[m][n], 0, 0, 0);
        }
        __builtin_amdgcn_s_setprio(0);
    }

    #pragma unroll
    for (int m = 0; m < 4; m++)
        #pragma unroll
        for (int n = 0; n < 4; n++)
            #pragma unroll
            for (int r = 0; r < 4; r++)
                sm[(m * 16 + gq * 4 + r) * MSTR + n * 16 + l15] = f2bf(silu_f(acc[m][n][r]));
    asm volatile("s_waitcnt lgkmcnt(0)" ::: "memory");

    f32x4 acc2[4][4];
    #pragma unroll
    for (int n = 0; n < 4; n++) {
        float bias = b_f2[n * 16 + l15];
        #pragma unroll
        for (int m = 0; m < 4; m++) acc2[m][n] = f32x4{bias, bias, bias, bias};
    }
    const short8* pkf2 = reinterpret_cast<const short8*>(pk + P_F2);
    #pragma unroll
    for (int s = 0; s < 2; s++) {
        short8 afr[4];
        #pragma unroll
        for (int m = 0; m < 4; m++)
            afr[m] = *reinterpret_cast<const short8*>(sm + (m * 16 + l15) * MSTR + s * 32 + kg);
        __builtin_amdgcn_s_setprio(1);
        #pragma unroll
        for (int n = 0; n < 4; n++) {
            short8 bfr = pkf2[(s * 4 + n) * 64 + lane];
            #pragma unroll
            for (int m = 0; m < 4; m++)
                acc2[m][n] = __builtin_amdgcn_mfma_f32_16x16x32_bf16(afr[m], bfr, acc2[m][n], 0, 0, 0);
        }
        __builtin_amdgcn_s_setprio(0);
    }

    float* ohb = out_h + (size_t)b * NN * 64;
    #pragma unroll
    for (int m = 0; m < 4; m++)
        #pragma unroll
        for (int r = 0; r < 4; r++) {
            int nd = n0 + m * 16 + gq * 4 + r;
            if (nd < NN) {
                #pragma unroll
                for (int n = 0; n < 4; n++)
                    ohb[(size_t)nd * 64 + n * 16 + l15] = ssgn_f(acc2[m][n][r]);
            }
        }

    const int node = n0 + lane;
    if (node < NN) {
        int c_i = off[node + 1] - off[node];
        float c = (float)(c_i < 1 ? 1 : c_i);
        float invc = fast_rcp(c);
        const float4 xv = *reinterpret_cast<const float4*>(x + ((size_t)b * NN + node) * 4);
        float* xop = out_x + ((size_t)b * NN + node) * 4;
        float4 xa = *reinterpret_cast<float4*>(xop);
        float4 r;
        r.x = xv.x + xa.x * invc;
        r.y = xv.y + xa.y * invc;
        r.z = xv.z + xa.z * invc;
        r.w = xv.w + xa.w * invc;
        *reinterpret_cast<float4*>(xop) = r;
    }
}

// ---------------------------------------------------------------------------
extern "C" void kernel_launch(void* const* d_in, const int* in_sizes, int n_in,
                              void* d_out, int out_size, void* d_ws, size_t ws_size,
                              hipStream_t stream) {
    const float* h    = (const float*)d_in[0];
    const float* x    = (const float*)d_in[1];
    const int*   ei   = (const int*)d_in[2];
    const float* ea   = (const float*)d_in[3];
    const float* w_e1 = (const float*)d_in[4];
    const float* b_e1 = (const float*)d_in[5];
    const float* w_e2 = (const float*)d_in[6];
    const float* b_e2 = (const float*)d_in[7];
    const float* w_f1 = (const float*)d_in[8];
    const float* b_f1 = (const float*)d_in[9];
    const float* w_f2 = (const float*)d_in[10];
    const float* b_f2 = (const float*)d_in[11];
    const float* w_c1 = (const float*)d_in[12];
    const float* b_c1 = (const float*)d_in[13];
    const float* w_c2 = (const float*)d_in[14];
    const float* smp  = (const float*)d_in[15];
    const float* omp  = (const float*)d_in[16];

    float* out   = (float*)d_out;
    float* agg   = out;
    float* out_x = out + (size_t)NB * NN * 64;

    char* ws = (char*)d_ws;
    int*   cnt_i = (int*)(ws + WS_CNT);
    int*   off   = (int*)(ws + WS_OFF);
    int*   cur   = (int*)(ws + WS_CUR);
    int*   eids  = (int*)(ws + WS_EIDS);
    short* pk    = (short*)(ws + WS_PK);
    short* hb16  = (short*)(ws + WS_HB);

    hipMemsetAsync(d_out, 0, (size_t)out_size * sizeof(float), stream);
    hipMemsetAsync(cnt_i, 0, (size_t)NN * sizeof(int), stream);

    pack_weights<<<15, 256, 0, stream>>>(w_e1, w_e2, w_c1, w_f1, w_f2, pk);
    conv_h<<<3125, 256, 0, stream>>>(h, hb16);

    const int eb = (EE + 255) / 256;
    hist_kernel<<<eb, 256, 0, stream>>>(ei, cnt_i);
    scan_kernel<<<1, 1024, 0, stream>>>(cnt_i, off, cur);
    scatter_kernel<<<eb, 256, 0, stream>>>(ei, cur, eids);

    const int edge_waves = NB * (EE / 64);            // 31250
    const int edge_blocks = (edge_waves + 3) / 4;     // 7813
    edge_kernel<<<edge_blocks, 256, 0, stream>>>(
        hb16, x, ei, ea, eids, b_e1, b_e2, b_c1, w_c2, pk,
        smp, omp, agg, out_x);

    const int node_waves = NB * ((NN + 63) / 64);
    const int node_blocks = (node_waves + 3) / 4;
    node_kernel<<<node_blocks, 256, 0, stream>>>(
        hb16, x, b_f1, b_f2, pk, off, agg, out_x);
}